// Round 7
// baseline (674.578 us; speedup 1.0000x reference)
//
#include <hip/hip_runtime.h>
#include <math.h>

#define B_  32
#define S_  2048
#define DV  1024
#define U_  1024

typedef __attribute__((ext_vector_type(8))) short bf16x8;
typedef __attribute__((ext_vector_type(4))) float f32x4;

__device__ inline unsigned short f2bf(float f) {
    unsigned int x = __float_as_uint(f);
    return (unsigned short)((x + 0x7fffu + ((x >> 16) & 1u)) >> 16);
}

__device__ inline uint4 pack8(float4 a, float4 b) {
    union { unsigned short s[8]; uint4 u; } p;
    p.s[0] = f2bf(a.x); p.s[1] = f2bf(a.y); p.s[2] = f2bf(a.z); p.s[3] = f2bf(a.w);
    p.s[4] = f2bf(b.x); p.s[5] = f2bf(b.y); p.s[6] = f2bf(b.z); p.s[7] = f2bf(b.w);
    return p.u;
}

__device__ inline float tanh_fast(float x) {
    float ax = fabsf(x);
    float e  = __expf(ax + ax);
    float t  = 1.0f - __fdividef(2.0f, e + 1.0f);
    return copysignf(t, x);
}

// async global->LDS, 16B per lane; LDS dest is the wave-uniform base.
__device__ __forceinline__ void gload16(const void* g, void* l) {
    __builtin_amdgcn_global_load_lds(
        (const __attribute__((address_space(1))) void*)g,
        (__attribute__((address_space(3))) void*)l,
        16, 0, 0);
}

#define ASM_VMCNT(N) asm volatile("s_waitcnt vmcnt(" #N ")" ::: "memory")
#define ASM_LGKM0()  do { asm volatile("s_waitcnt lgkmcnt(0)" ::: "memory"); \
                          __builtin_amdgcn_sched_barrier(0); } while (0)

// ---------------- prep_small: W1T | projq_full | zero scores ----------------
// block ranges (all independent):
//   [0,256)    prep_w1t  (W1 -> W1T bf16, 64x64 transpose tiles)
//   [256,384)  projq     (t[b,u] = b1[u]+b2[u]+q[b,:]@W2[:,u], no atomics)
//   [384,640)  zero scores (65536 floats; scores kernel accumulates atomically)
__global__ __launch_bounds__(256)
void prep_small(const float* __restrict__ W1, unsigned short* __restrict__ W1T,
                const float* __restrict__ query, const float* __restrict__ W2,
                const float* __restrict__ b1, const float* __restrict__ b2,
                float* __restrict__ t, float* __restrict__ scores) {
    const int bid = blockIdx.x;
    const int tid = threadIdx.x;

    if (bid < 256) {
        __shared__ float tile[64][65];
        int k0 = (bid & 15) * 64, u0 = (bid >> 4) * 64;
        int lr = tid >> 4, lc = (tid & 15) * 4;
#pragma unroll
        for (int j = 0; j < 4; ++j) {
            float4 f = *(const float4*)&W1[(size_t)(k0 + lr + j * 16) * U_ + u0 + lc];
            tile[lr + j * 16][lc + 0] = f.x; tile[lr + j * 16][lc + 1] = f.y;
            tile[lr + j * 16][lc + 2] = f.z; tile[lr + j * 16][lc + 3] = f.w;
        }
        __syncthreads();
        int ur = tid >> 2, kq = (tid & 3) * 16;
        union { unsigned short s[8]; uint4 u; } p0, p1;
#pragma unroll
        for (int e = 0; e < 8; ++e) p0.s[e] = f2bf(tile[kq + e][ur]);
#pragma unroll
        for (int e = 0; e < 8; ++e) p1.s[e] = f2bf(tile[kq + 8 + e][ur]);
        unsigned short* dst = W1T + (size_t)(u0 + ur) * 1024 + k0 + kq;
        *(uint4*)dst       = p0.u;
        *(uint4*)(dst + 8) = p1.u;
    } else if (bid < 384) {
        __shared__ float qs2[1024];
        int i = bid - 256;
        int b = i >> 2, uq = i & 3;
        for (int j = tid; j < 1024; j += 256) qs2[j] = query[b * DV + j];
        __syncthreads();
        int u = uq * 256 + tid;
        float a0 = 0.f, a1 = 0.f, a2 = 0.f, a3 = 0.f;
        float a4 = 0.f, a5 = 0.f, a6 = 0.f, a7 = 0.f;
        const float* w = W2 + u;
        for (int k = 0; k < 1024; k += 8) {
            a0 += qs2[k + 0] * w[(size_t)(k + 0) * U_];
            a1 += qs2[k + 1] * w[(size_t)(k + 1) * U_];
            a2 += qs2[k + 2] * w[(size_t)(k + 2) * U_];
            a3 += qs2[k + 3] * w[(size_t)(k + 3) * U_];
            a4 += qs2[k + 4] * w[(size_t)(k + 4) * U_];
            a5 += qs2[k + 5] * w[(size_t)(k + 5) * U_];
            a6 += qs2[k + 6] * w[(size_t)(k + 6) * U_];
            a7 += qs2[k + 7] * w[(size_t)(k + 7) * U_];
        }
        t[b * U_ + u] = b1[u] + b2[u]
                      + ((a0 + a1) + (a2 + a3)) + ((a4 + a5) + (a6 + a7));
    } else {
        scores[(bid - 384) * 256 + tid] = 0.f;
    }
}

// ---------------- cvt_lines: values fp32 -> K-tiled bf16, line-contiguous ---
// Same output layout as R4/R5 (byte-identical LDS image for the scores kernel):
//   dst = stile*512KB + kt*32KB + h*16KB + r*128 + pchunk*16,
//   pchunk p holds k-chunk (p ^ (r&7)), kk ascending within chunk.
// One thread per 128-B line: reads 256 B contiguous fp32, writes its whole
// line (8x 16 B within one 128-B span). Block (stile,kt) writes 32 KB
// contiguous. Source chunk indices are COMPILE-TIME (rule #20: runtime
// ext-vector indexing would spill); the XOR lands on the store address.
__global__ __launch_bounds__(256)
void cvt_lines(const float* __restrict__ v, char* __restrict__ o) {
    const int bid   = blockIdx.x;        // 4096 = 256 stiles x 16 kt
    const int stile = bid >> 4;
    const int kt    = bid & 15;
    const int tid   = threadIdx.x;       // 256: h = tid>>7, r = tid&127
    const int h     = tid >> 7;
    const int r     = tid & 127;
    const int row   = stile * 256 + h * 128 + r;
    const float4* src = (const float4*)(v + (size_t)row * 1024 + kt * 64);
    float4 f[16];
#pragma unroll
    for (int j = 0; j < 16; ++j) f[j] = src[j];
    char* dst = o + (size_t)stile * 524288 + kt * 32768 + h * 16384 + r * 128;
    const int rx = r & 7;
#pragma unroll
    for (int c = 0; c < 8; ++c) {
        uint4 w = pack8(f[2 * c], f[2 * c + 1]);       // compile-time index
        *(uint4*)(dst + ((c ^ rx) << 4)) = w;          // runtime addr: ok
    }
}

// ---------------- K2: 256x256 tile, BK=64, 8-phase, TILED A source ----------
// (verbatim R5 kernel — proven 170 us)
#define MFMA16(MB, NB)                                                          \
    _Pragma("unroll") for (int ks = 0; ks < 2; ++ks)                            \
    _Pragma("unroll") for (int n = 0; n < 2; ++n)                               \
    _Pragma("unroll") for (int m = 0; m < 4; ++m)                               \
        acc[(MB)+m][(NB)+n] = __builtin_amdgcn_mfma_f32_16x16x32_bf16(          \
            af[m][ks], bf[n][ks], acc[(MB)+m][(NB)+n], 0, 0, 0);

__launch_bounds__(512, 2)
__global__ void scores_mfma8(const char* __restrict__ AbfT,
                             const unsigned short* __restrict__ W1T,
                             const float* __restrict__ tvec,
                             const float* __restrict__ V,
                             float* __restrict__ scores) {
    __shared__ __align__(16) char lds[131072];   // 128 KB

    const int tid  = threadIdx.x;
    const int lane = tid & 63;
    const int wave = tid >> 6;        // 0..7
    const int wm   = wave >> 2;       // 0..1  (row half of 256)
    const int wn   = wave & 3;        // 0..3  (64-col strip of 256)
    const int l15  = lane & 15;
    const int lq   = lane >> 4;       // 0..3

    const int id    = blockIdx.x;
    const int wg    = (id & 7) * 128 + (id >> 3);
    const int utile = wg & 3;                    // 4 u-tiles of 256
    const int stile = wg >> 2;                   // 256 s-tiles of 256
    const size_t row0 = (size_t)stile * 256;
    const int b       = (int)(row0 >> 11);
    const int s_local = (int)(row0 & 2047);
    const int u0      = utile * 256;

    const char* aBase = AbfT + (size_t)stile * 524288 + wave * 1024 + lane * 16;
    const int rowst = wave * 8 + (lane >> 3);
    const int kch8  = ((lane & 7) ^ ((lane >> 3) & 7)) * 8;
    const unsigned short* bSrc = W1T + (size_t)(u0 + rowst) * 1024 + kch8;
    char* const dstW = lds + wave * 1024;

    const int ao0 = wm * 16384 + l15 * 128 + ((lq ^ (l15 & 7)) << 4);
    const int ao1 = ao0 ^ 64;
    const int bo0 = 32768 + (wn >> 1) * 16384 + (wn & 1) * 8192
                  + l15 * 128 + ((lq ^ (l15 & 7)) << 4);
    const int bo1 = bo0 ^ 64;

    f32x4 acc[8][4];
#pragma unroll
    for (int m = 0; m < 8; ++m)
#pragma unroll
        for (int n = 0; n < 4; ++n) acc[m][n] = (f32x4)0.f;

    bf16x8 af[4][2];
    bf16x8 bf[2][2];

    auto stageA = [&](size_t gOff, int dOff) {
        gload16(aBase + gOff,        dstW + dOff);
        gload16(aBase + gOff + 8192, dstW + dOff + 8192);
    };
    auto stageB = [&](const unsigned short* s, int dOff) {
        gload16(s,             dstW + dOff);
        gload16(s + 64 * 1024, dstW + dOff + 8192);
    };
    auto readA4 = [&](int base) {
#pragma unroll
        for (int m = 0; m < 4; ++m) {
            af[m][0] = *(const bf16x8*)(lds + base + m * 2048 + ao0);
            af[m][1] = *(const bf16x8*)(lds + base + m * 2048 + ao1);
        }
    };
    auto readB2 = [&](int base) {
#pragma unroll
        for (int n = 0; n < 2; ++n) {
            bf[n][0] = *(const bf16x8*)(lds + base + n * 2048 + bo0);
            bf[n][1] = *(const bf16x8*)(lds + base + n * 2048 + bo1);
        }
    };

    stageA(0,     0);
    stageA(16384, 16384);
    stageB(bSrc,          32768);
    stageB(bSrc + 131072, 49152);
    stageA(32768, 65536);
    __builtin_amdgcn_sched_barrier(0);
    ASM_VMCNT(2);
    __builtin_amdgcn_s_barrier();
    __builtin_amdgcn_sched_barrier(0);

    for (int it = 0; it < 8; ++it) {
        const bool pf = (it < 7);
        const size_t aIt = (size_t)it * 65536;
        // ---------- phase 0: d0, m0-3 x n0-1 ----------
        readA4(0);
        readB2(0);
        stageA(aIt + 49152, 81920);                  // A1(kt1) -> d1
        __builtin_amdgcn_s_barrier();
        ASM_LGKM0();
        __builtin_amdgcn_s_setprio(1);
        MFMA16(0, 0);
        __builtin_amdgcn_s_setprio(0);
        __builtin_amdgcn_s_barrier();
        // ---------- phase 1: d0, m0-3 x n2-3 ----------
        readB2(2 * 2048);
        stageB(bSrc + 64, 98304);                    // B0(kt1) -> d1
        __builtin_amdgcn_s_barrier();
        ASM_LGKM0();
        __builtin_amdgcn_s_setprio(1);
        MFMA16(0, 2);
        __builtin_amdgcn_s_setprio(0);
        __builtin_amdgcn_s_barrier();
        // ---------- phase 2: d0, m4-7 x n2-3 ----------
        readA4(4 * 2048);
        stageB(bSrc + 64 + 131072, 114688);          // B1(kt1) -> d1
        __builtin_amdgcn_s_barrier();
        ASM_LGKM0();
        __builtin_amdgcn_s_setprio(1);
        MFMA16(4, 2);
        __builtin_amdgcn_s_setprio(0);
        __builtin_amdgcn_s_barrier();
        // ---------- phase 3: d0, m4-7 x n0-1 ----------
        readB2(0);
        if (pf) stageA(aIt + 65536, 0);              // A0(kt2) -> d0
        __builtin_amdgcn_s_barrier();
        ASM_LGKM0();
        __builtin_amdgcn_s_setprio(1);
        MFMA16(4, 0);
        __builtin_amdgcn_s_setprio(0);
        __builtin_amdgcn_sched_barrier(0);
        if (pf) { ASM_VMCNT(2); } else { ASM_VMCNT(0); }   // d1 (kt1) landed
        __builtin_amdgcn_s_barrier();
        __builtin_amdgcn_sched_barrier(0);
        // ---------- phase 4: d1, m0-3 x n0-1 ----------
        readA4(65536);
        readB2(65536);
        if (pf) stageA(aIt + 81920, 16384);          // A1(kt2) -> d0
        __builtin_amdgcn_s_barrier();
        ASM_LGKM0();
        __builtin_amdgcn_s_setprio(1);
        MFMA16(0, 0);
        __builtin_amdgcn_s_setprio(0);
        __builtin_amdgcn_s_barrier();
        // ---------- phase 5: d1, m0-3 x n2-3 ----------
        readB2(65536 + 2 * 2048);
        if (pf) stageB(bSrc + 128, 32768);           // B0(kt2) -> d0
        __builtin_amdgcn_s_barrier();
        ASM_LGKM0();
        __builtin_amdgcn_s_setprio(1);
        MFMA16(0, 2);
        __builtin_amdgcn_s_setprio(0);
        __builtin_amdgcn_s_barrier();
        // ---------- phase 6: d1, m4-7 x n2-3 ----------
        if (pf) stageB(bSrc + 128 + 131072, 49152);  // B1(kt2) -> d0
        readA4(65536 + 4 * 2048);
        __builtin_amdgcn_s_barrier();
        ASM_LGKM0();
        __builtin_amdgcn_s_setprio(1);
        MFMA16(4, 2);
        __builtin_amdgcn_s_setprio(0);
        __builtin_amdgcn_s_barrier();
        // ---------- phase 7: d1, m4-7 x n0-1 ----------
        readB2(65536);
        if (pf) stageA(aIt + 98304, 65536);          // A0(kt3) -> d1
        __builtin_amdgcn_s_barrier();
        ASM_LGKM0();
        __builtin_amdgcn_s_setprio(1);
        MFMA16(4, 0);
        __builtin_amdgcn_s_setprio(0);
        __builtin_amdgcn_sched_barrier(0);
        if (pf) { ASM_VMCNT(2); }                    // d0 (kt2) landed
        __builtin_amdgcn_s_barrier();
        __builtin_amdgcn_sched_barrier(0);

        bSrc += 128;
    }

    // epilogue: score[row] += sum_u tanh(P + t[b,u]) * V[u]
    __syncthreads();
    float* fscore = (float*)lds;
    if (tid < 256) fscore[tid] = 0.f;
    __syncthreads();
    float tu[4], vu[4];
#pragma unroll
    for (int n = 0; n < 4; ++n) {
        int u = u0 + wn * 64 + n * 16 + l15;
        tu[n] = tvec[b * U_ + u];
        vu[n] = V[u];
    }
#pragma unroll
    for (int m = 0; m < 8; ++m) {
#pragma unroll
        for (int r = 0; r < 4; ++r) {
            float p = 0.f;
#pragma unroll
            for (int n = 0; n < 4; ++n) p += tanh_fast(acc[m][n][r] + tu[n]) * vu[n];
            p += __shfl_xor(p, 1);
            p += __shfl_xor(p, 2);
            p += __shfl_xor(p, 4);
            p += __shfl_xor(p, 8);
            if (l15 == 0) atomicAdd(&fscore[wm * 128 + m * 16 + lq * 4 + r], p);
        }
    }
    __syncthreads();
    if (tid < 256) atomicAdd(&scores[(size_t)b * S_ + s_local + tid], fscore[tid]);
}

// ---------------- sm_ctx_part: softmax + partial context, NO out atomics ----
// block (b, sc): redundant softmax stats (bit-identical across blocks), write
// wout chunk with plain stores, stream 128 value-rows, write the 1024-float
// partial sum to ws ctxp[(b*16+sc)*1024] with plain float4 stores.
__global__ __launch_bounds__(256)
void sm_ctx_part(const float* __restrict__ scores, const float* __restrict__ values,
                 float* __restrict__ wout, float* __restrict__ ctxp) {
    const int b   = blockIdx.x;     // 32
    const int sc  = blockIdx.y;     // 16 chunks of 128 s
    const int tid = threadIdx.x;    // 256
    __shared__ float red[256];
    __shared__ float ws_[128];

    float v[8];
    float m = -1e30f;
#pragma unroll
    for (int i = 0; i < 8; ++i) {
        v[i] = scores[(size_t)b * S_ + tid + i * 256];
        m = fmaxf(m, v[i]);
    }
    red[tid] = m; __syncthreads();
    for (int off = 128; off > 0; off >>= 1) {
        if (tid < off) red[tid] = fmaxf(red[tid], red[tid + off]);
        __syncthreads();
    }
    m = red[0];
    __syncthreads();
    float s = 0.f;
#pragma unroll
    for (int i = 0; i < 8; ++i) s += __expf(v[i] - m);
    red[tid] = s; __syncthreads();
    for (int off = 128; off > 0; off >>= 1) {
        if (tid < off) red[tid] += red[tid + off];
        __syncthreads();
    }
    float inv = 1.f / red[0];
    __syncthreads();

    if (tid < 128) {
        float x = scores[(size_t)b * S_ + sc * 128 + tid];
        float w = __expf(x - m) * inv;
        ws_[tid] = w;
        wout[(size_t)b * S_ + sc * 128 + tid] = w;
    }
    __syncthreads();

    const float4* vp = (const float4*)(values + ((size_t)b * S_ + sc * 128) * DV) + tid;
    float ax = 0.f, ay = 0.f, az = 0.f, aw = 0.f;
#pragma unroll 4
    for (int s2 = 0; s2 < 128; ++s2) {
        float4 vv = vp[(size_t)s2 * 256];
        float wv = ws_[s2];
        ax += wv * vv.x; ay += wv * vv.y; az += wv * vv.z; aw += wv * vv.w;
    }
    float4 outv; outv.x = ax; outv.y = ay; outv.z = az; outv.w = aw;
    *(float4*)(ctxp + ((size_t)(b * 16 + sc)) * 1024 + tid * 4) = outv;
}

// ---------------- ctx_reduce: fan-in 16 partials, plain stores to out -------
__global__ __launch_bounds__(256)
void ctx_reduce(const float* __restrict__ ctxp, float* __restrict__ ctx) {
    const int b  = blockIdx.x;      // 32
    const int dq = blockIdx.y;      // 4
    const int d  = dq * 256 + threadIdx.x;
    const float* p = ctxp + (size_t)b * 16 * 1024 + d;
    float s = 0.f;
#pragma unroll
    for (int sc = 0; sc < 16; ++sc) s += p[sc * 1024];
    ctx[b * DV + d] = s;
}

// ================= legacy kernels (low ws fallback path) ====================
__global__ void init_kernel(const float* __restrict__ b1, const float* __restrict__ b2,
                            float* __restrict__ t, float* __restrict__ ctx,
                            float* __restrict__ scores) {
    int i = blockIdx.x * 256 + threadIdx.x;   // 65536
    scores[i] = 0.f;
    if (i < B_ * U_) {
        int u = i & (U_ - 1);
        t[i]   = b1[u] + b2[u];
        ctx[i] = 0.f;
    }
}

__global__ void projq_kernel(const float* __restrict__ q, const float* __restrict__ W2,
                             float* __restrict__ t) {
    int b  = blockIdx.x;
    int ks = blockIdx.y;
    int tid = threadIdx.x;
    __shared__ float qs[64];
    if (tid < 64) qs[tid] = q[b * DV + ks * 64 + tid];
    __syncthreads();
    float a0 = 0.f, a1 = 0.f, a2 = 0.f, a3 = 0.f;
    const float* w = W2 + (size_t)(ks * 64) * U_;
    for (int d = 0; d < 64; ++d) {
        float qd = qs[d];
        const float* wr = w + (size_t)d * U_ + tid;
        a0 += qd * wr[0];
        a1 += qd * wr[256];
        a2 += qd * wr[512];
        a3 += qd * wr[768];
    }
    atomicAdd(&t[b * U_ + tid      ], a0);
    atomicAdd(&t[b * U_ + tid + 256], a1);
    atomicAdd(&t[b * U_ + tid + 512], a2);
    atomicAdd(&t[b * U_ + tid + 768], a3);
}

__launch_bounds__(256, 2)
__global__ void scores_vec(const float* __restrict__ values, const float* __restrict__ W1,
                           const float* __restrict__ t, const float* __restrict__ V,
                           float* __restrict__ scores) {
    __shared__ float vA[16][132];
    __shared__ float vB[16][68];
    __shared__ float fscore[128];
    const int b   = blockIdx.y;
    const int s0  = blockIdx.x * 128;
    const int tid = threadIdx.x;
    const int tx  = tid & 15, ty = tid >> 4;
    if (tid < 128) fscore[tid] = 0.f;
    const float* vbase = values + ((size_t)b * S_ + s0) * (size_t)DV;
    const int lm = tid >> 2, lkq = (tid & 3) * 4;
    const int lbk = tid >> 4, lbj = (tid & 15) * 4;
    for (int nt = 0; nt < U_ / 64; ++nt) {
        const int u0 = nt * 64;
        float acc[8][4];
#pragma unroll
        for (int i = 0; i < 8; ++i)
#pragma unroll
            for (int j = 0; j < 4; ++j) acc[i][j] = 0.f;
        for (int k0 = 0; k0 < DV; k0 += 16) {
            __syncthreads();
            const float4 v0 = *(const float4*)(vbase + (size_t)lm * DV + k0 + lkq);
            const float4 v1 = *(const float4*)(vbase + (size_t)(lm + 64) * DV + k0 + lkq);
            vA[lkq + 0][lm] = v0.x; vA[lkq + 1][lm] = v0.y;
            vA[lkq + 2][lm] = v0.z; vA[lkq + 3][lm] = v0.w;
            vA[lkq + 0][lm + 64] = v1.x; vA[lkq + 1][lm + 64] = v1.y;
            vA[lkq + 2][lm + 64] = v1.z; vA[lkq + 3][lm + 64] = v1.w;
            *(float4*)&vB[lbk][lbj] = *(const float4*)(W1 + (size_t)(k0 + lbk) * U_ + u0 + lbj);
            __syncthreads();
#pragma unroll
            for (int k = 0; k < 16; ++k) {
                float4 va0 = *(const float4*)&vA[k][ty * 8];
                float4 va1 = *(const float4*)&vA[k][ty * 8 + 4];
                float4 vb  = *(const float4*)&vB[k][tx * 4];
                float a_[8] = {va0.x, va0.y, va0.z, va0.w, va1.x, va1.y, va1.z, va1.w};
                float b_[4] = {vb.x, vb.y, vb.z, vb.w};
#pragma unroll
                for (int i = 0; i < 8; ++i)
#pragma unroll
                    for (int j = 0; j < 4; ++j) acc[i][j] += a_[i] * b_[j];
            }
        }
        float tq[4], vv[4];
#pragma unroll
        for (int j = 0; j < 4; ++j) {
            int u = u0 + tx * 4 + j;
            tq[j] = t[b * U_ + u];
            vv[j] = V[u];
        }
#pragma unroll
        for (int i = 0; i < 8; ++i) {
            float p = 0.f;
#pragma unroll
            for (int j = 0; j < 4; ++j) p += tanhf(acc[i][j] + tq[j]) * vv[j];
            p += __shfl_down(p, 8, 16);
            p += __shfl_down(p, 4, 16);
            p += __shfl_down(p, 2, 16);
            p += __shfl_down(p, 1, 16);
            if (tx == 0) fscore[ty * 8 + i] += p;
        }
    }
    __syncthreads();
    if (tid < 128) scores[(size_t)b * S_ + s0 + tid] = fscore[tid];
}

__global__ void softmax_kernel(const float* __restrict__ scores, float* __restrict__ wout) {
    int b = blockIdx.x;
    int tid = threadIdx.x;
    __shared__ float red[256];
    float v[8];
    float m = -1e30f;
#pragma unroll
    for (int i = 0; i < 8; ++i) {
        v[i] = scores[(size_t)b * S_ + tid + i * 256];
        m = fmaxf(m, v[i]);
    }
    red[tid] = m; __syncthreads();
    for (int off = 128; off > 0; off >>= 1) {
        if (tid < off) red[tid] = fmaxf(red[tid], red[tid + off]);
        __syncthreads();
    }
    m = red[0];
    __syncthreads();
    float s = 0.f;
#pragma unroll
    for (int i = 0; i < 8; ++i) { v[i] = __expf(v[i] - m); s += v[i]; }
    red[tid] = s; __syncthreads();
    for (int off = 128; off > 0; off >>= 1) {
        if (tid < off) red[tid] += red[tid + off];
        __syncthreads();
    }
    float inv = 1.f / red[0];
#pragma unroll
    for (int i = 0; i < 8; ++i) wout[(size_t)b * S_ + tid + i * 256] = v[i] * inv;
}

__global__ void context_kernel(const float* __restrict__ values, const float* __restrict__ w,
                               float* __restrict__ ctx) {
    int b   = blockIdx.x;
    int sc  = blockIdx.y;
    int tid = threadIdx.x;
    __shared__ float ws_[128];
    if (tid < 128) ws_[tid] = w[(size_t)b * S_ + sc * 128 + tid];
    __syncthreads();
    const float4* vp = (const float4*)(values + ((size_t)b * S_ + sc * 128) * DV) + tid;
    float ax = 0.f, ay = 0.f, az = 0.f, aw = 0.f;
#pragma unroll 4
    for (int s = 0; s < 128; ++s) {
        float4 v = vp[(size_t)s * 256];
        float wv = ws_[s];
        ax += wv * v.x; ay += wv * v.y; az += wv * v.z; aw += wv * v.w;
    }
    float* c = ctx + b * DV + tid * 4;
    atomicAdd(c + 0, ax); atomicAdd(c + 1, ay);
    atomicAdd(c + 2, az); atomicAdd(c + 3, aw);
}

// ---------------- launch ----------------------------------------------------
extern "C" void kernel_launch(void* const* d_in, const int* in_sizes, int n_in,
                              void* d_out, int out_size, void* d_ws, size_t ws_size,
                              hipStream_t stream) {
    const float* query  = (const float*)d_in[0];
    const float* values = (const float*)d_in[1];
    const float* W1     = (const float*)d_in[2];
    const float* b1     = (const float*)d_in[3];
    const float* W2     = (const float*)d_in[4];
    const float* b2     = (const float*)d_in[5];
    const float* V      = (const float*)d_in[6];
    // bV (d_in[7]) shifts all scores equally -> softmax-invariant.

    float* out  = (float*)d_out;
    float* ctx  = out;                 // [32, 1024]
    float* wout = out + B_ * DV;       // [32, 2048]

    char* ws = (char*)d_ws;
    const size_t W1T_BYTES  = (size_t)U_ * DV * 2;             // 2 MB
    const size_t T_BYTES    = (size_t)B_ * U_ * 4;             // 128 KB
    const size_t SC_BYTES   = (size_t)B_ * S_ * 4;             // 256 KB
    const size_t CTXP_BYTES = (size_t)B_ * 16 * DV * 4;        // 2 MB
    const size_t ABF_BYTES  = (size_t)B_ * S_ * DV * 2;        // 128 MB

    if (ws_size >= W1T_BYTES + T_BYTES + SC_BYTES + CTXP_BYTES + ABF_BYTES) {
        // fast path: tiled bf16 A (line-contiguous cvt), 8-phase MFMA,
        // softmax+partial-context with ZERO atomics to d_out.
        unsigned short* W1T = (unsigned short*)ws;
        float* t      = (float*)(ws + W1T_BYTES);
        float* scores = t + B_ * U_;
        float* ctxp   = scores + B_ * S_;
        char*  AbfT   = (char*)(ctxp + B_ * 16 * DV);

        prep_small  <<<dim3(640),    256, 0, stream>>>(W1, W1T, query, W2,
                                                       b1, b2, t, scores);
        cvt_lines   <<<dim3(4096),   256, 0, stream>>>(values, AbfT);
        scores_mfma8<<<dim3(1024),   512, 0, stream>>>(AbfT, W1T, t, V, scores);
        sm_ctx_part <<<dim3(32, 16), 256, 0, stream>>>(scores, values, wout, ctxp);
        ctx_reduce  <<<dim3(32, 4),  256, 0, stream>>>(ctxp, ctx);
    } else {
        // low path: round-1 fp32 vector kernel (384 KB ws, proven)
        float* t      = (float*)ws;
        float* scores = t + B_ * U_;

        init_kernel   <<<dim3(256),      256, 0, stream>>>(b1, b2, t, ctx, scores);
        projq_kernel  <<<dim3(32, 16),   256, 0, stream>>>(query, W2, t);
        scores_vec    <<<dim3(16, 32),   256, 0, stream>>>(values, W1, t, V, scores);
        softmax_kernel<<<dim3(32),       256, 0, stream>>>(scores, wout);
        context_kernel<<<dim3(32, 16),   256, 0, stream>>>(values, wout, ctx);
    }
}

// Round 8
// 646.745 us; speedup vs baseline: 1.0430x; 1.0430x over previous
//
#include <hip/hip_runtime.h>
#include <math.h>

#define B_  32
#define S_  2048
#define DV  1024
#define U_  1024

typedef __attribute__((ext_vector_type(8))) short bf16x8;
typedef __attribute__((ext_vector_type(4))) float f32x4;

__device__ inline unsigned short f2bf(float f) {
    unsigned int x = __float_as_uint(f);
    return (unsigned short)((x + 0x7fffu + ((x >> 16) & 1u)) >> 16);
}

__device__ inline uint4 pack8(float4 a, float4 b) {
    union { unsigned short s[8]; uint4 u; } p;
    p.s[0] = f2bf(a.x); p.s[1] = f2bf(a.y); p.s[2] = f2bf(a.z); p.s[3] = f2bf(a.w);
    p.s[4] = f2bf(b.x); p.s[5] = f2bf(b.y); p.s[6] = f2bf(b.z); p.s[7] = f2bf(b.w);
    return p.u;
}

__device__ inline float tanh_fast(float x) {
    float ax = fabsf(x);
    float e  = __expf(ax + ax);
    float t  = 1.0f - __fdividef(2.0f, e + 1.0f);
    return copysignf(t, x);
}

// async global->LDS, 16B per lane; LDS dest is the wave-uniform base.
__device__ __forceinline__ void gload16(const void* g, void* l) {
    __builtin_amdgcn_global_load_lds(
        (const __attribute__((address_space(1))) void*)g,
        (__attribute__((address_space(3))) void*)l,
        16, 0, 0);
}

#define ASM_VMCNT(N) asm volatile("s_waitcnt vmcnt(" #N ")" ::: "memory")
#define ASM_LGKM0()  do { asm volatile("s_waitcnt lgkmcnt(0)" ::: "memory"); \
                          __builtin_amdgcn_sched_barrier(0); } while (0)

// ---------------- prep_small: W1T | projq_full | zero scores ----------------
__global__ __launch_bounds__(256)
void prep_small(const float* __restrict__ W1, unsigned short* __restrict__ W1T,
                const float* __restrict__ query, const float* __restrict__ W2,
                const float* __restrict__ b1, const float* __restrict__ b2,
                float* __restrict__ t, float* __restrict__ scores) {
    const int bid = blockIdx.x;
    const int tid = threadIdx.x;

    if (bid < 256) {
        __shared__ float tile[64][65];
        int k0 = (bid & 15) * 64, u0 = (bid >> 4) * 64;
        int lr = tid >> 4, lc = (tid & 15) * 4;
#pragma unroll
        for (int j = 0; j < 4; ++j) {
            float4 f = *(const float4*)&W1[(size_t)(k0 + lr + j * 16) * U_ + u0 + lc];
            tile[lr + j * 16][lc + 0] = f.x; tile[lr + j * 16][lc + 1] = f.y;
            tile[lr + j * 16][lc + 2] = f.z; tile[lr + j * 16][lc + 3] = f.w;
        }
        __syncthreads();
        int ur = tid >> 2, kq = (tid & 3) * 16;
        union { unsigned short s[8]; uint4 u; } p0, p1;
#pragma unroll
        for (int e = 0; e < 8; ++e) p0.s[e] = f2bf(tile[kq + e][ur]);
#pragma unroll
        for (int e = 0; e < 8; ++e) p1.s[e] = f2bf(tile[kq + 8 + e][ur]);
        unsigned short* dst = W1T + (size_t)(u0 + ur) * 1024 + k0 + kq;
        *(uint4*)dst       = p0.u;
        *(uint4*)(dst + 8) = p1.u;
    } else if (bid < 384) {
        __shared__ float qs2[1024];
        int i = bid - 256;
        int b = i >> 2, uq = i & 3;
        for (int j = tid; j < 1024; j += 256) qs2[j] = query[b * DV + j];
        __syncthreads();
        int u = uq * 256 + tid;
        float a0 = 0.f, a1 = 0.f, a2 = 0.f, a3 = 0.f;
        float a4 = 0.f, a5 = 0.f, a6 = 0.f, a7 = 0.f;
        const float* w = W2 + u;
        for (int k = 0; k < 1024; k += 8) {
            a0 += qs2[k + 0] * w[(size_t)(k + 0) * U_];
            a1 += qs2[k + 1] * w[(size_t)(k + 1) * U_];
            a2 += qs2[k + 2] * w[(size_t)(k + 2) * U_];
            a3 += qs2[k + 3] * w[(size_t)(k + 3) * U_];
            a4 += qs2[k + 4] * w[(size_t)(k + 4) * U_];
            a5 += qs2[k + 5] * w[(size_t)(k + 5) * U_];
            a6 += qs2[k + 6] * w[(size_t)(k + 6) * U_];
            a7 += qs2[k + 7] * w[(size_t)(k + 7) * U_];
        }
        t[b * U_ + u] = b1[u] + b2[u]
                      + ((a0 + a1) + (a2 + a3)) + ((a4 + a5) + (a6 + a7));
    } else {
        scores[(bid - 384) * 256 + tid] = 0.f;
    }
}

// ---------------- K2 v7: 256x256, BK=64, 8-phase, fp32-A DEEP reg-staged ----
// No cvt pass, no AbfT. A: fp32 from row-major values, f2bf in-register,
// ds_write with the XOR swizzle (bit-identical LDS image to R5's proven
// kernel). B: gload16 as R5. Compute body/frag reads/MFMA/epilogue: verbatim.
//
// Deep-prefetch ledger (the R6 fix). Sets (4x float4 each):
//   P: d1.A1 data (kt=2it+1), issued prev-ph4, WRITTEN ph0
//   Q: d0.A0 (kt=2it+2),      issued ph0,      written ph3   [pf]
//   R: d0.A1 (kt=2it+2),      issued ph0,      written ph4   [pf]
//   S: d1.A0 (kt=2it+3),      issued ph4,      written ph7   [pf]
// VMEM issue order/iter: [Q4 R4] ph0, B2 ph1, B2 ph2, [S4 P'4] ph4, B2 ph5,
// B2 ph6.  Waits (in-order vmcnt retirement):
//   ph3:  vmcnt(8)  -> retires Q (3 phases old; leaves R+B1a+B1b)
//   ph3-end: vmcnt(0) -> retires R (3 ph) + d1.B (1.5 ph, L2-hot)  [== R5 aging]
//   ph4:  write R, NO wait needed (drained at ph3-end)
//   ph7:  vmcnt(8)  -> retires S (3 phases old; leaves P'+B0a+B0b)
//   ph7-end: vmcnt(0) -> retires P' (3.5 ph) + d0.B (1.5 ph, L2-hot)
// => vmcnt==0 at every iteration boundary; every A load gets >=3 phases.
// WAR audit (write vs last ds_read of target region, barrier between):
//   P->d1.A1 ph0 (last read prev ph6) | Q->d0.A0 ph3 (ph2) |
//   R->d0.A1 ph4 (ph2) | S->d1.A0 ph7 (ph6).  ds_write visibility: each
//   phase's lgkm0 (before the phase-end barrier... after first barrier) drains
//   the writer's ds_write before any later-phase reader (R6-proven pattern).
#define MFMA16(MB, NB)                                                          \
    _Pragma("unroll") for (int ks = 0; ks < 2; ++ks)                            \
    _Pragma("unroll") for (int n = 0; n < 2; ++n)                               \
    _Pragma("unroll") for (int m = 0; m < 4; ++m)                               \
        acc[(MB)+m][(NB)+n] = __builtin_amdgcn_mfma_f32_16x16x32_bf16(          \
            af[m][ks], bf[n][ks], acc[(MB)+m][(NB)+n], 0, 0, 0);

#define ISSUEA(Sa, Sb, Sc, Sd, kt, h) do {                                      \
    const float4* _s = (const float4*)(aRow + (size_t)(h) * 131072 + (kt) * 64);\
    Sa = _s[0]; Sb = _s[1]; Sc = _s[2]; Sd = _s[3]; } while (0)

#define WRITEA(Sa, Sb, Sc, Sd, dOff) do {                                       \
    *(uint4*)(lds + (dOff) + wO0) = pack8(Sa, Sb);                              \
    *(uint4*)(lds + (dOff) + wO1) = pack8(Sc, Sd); } while (0)

__launch_bounds__(512, 2)
__global__ void scores_mfma8g(const float* __restrict__ values,
                              const unsigned short* __restrict__ W1T,
                              const float* __restrict__ tvec,
                              const float* __restrict__ V,
                              float* __restrict__ scores) {
    __shared__ __align__(16) char lds[131072];   // 128 KB -> 1 block/CU

    const int tid  = threadIdx.x;
    const int lane = tid & 63;
    const int wave = tid >> 6;        // 0..7
    const int wm   = wave >> 2;       // row half of 256
    const int wn   = wave & 3;        // 64-col strip of 256
    const int l15  = lane & 15;
    const int lq   = lane >> 4;

    const int id    = blockIdx.x;
    const int wg    = (id & 7) * 128 + (id >> 3);
    const int utile = wg & 3;                    // 4 u-tiles of 256
    const int stile = wg >> 2;                   // 256 s-tiles of 256
    const size_t row0 = (size_t)stile * 256;
    const int b       = (int)(row0 >> 11);
    const int s_local = (int)(row0 & 2047);
    const int u0      = utile * 256;

    // B staging (unchanged from R5): inverse-XOR per-lane source, gload16
    const int rowst = wave * 8 + (lane >> 3);
    const int kch8  = ((lane & 7) ^ ((lane >> 3) & 7)) * 8;
    const unsigned short* bSrc = W1T + (size_t)(u0 + rowst) * 1024 + kch8;
    char* const dstW = lds + wave * 1024;

    // A reg-stage constants: thread = (row rA, 16-float chunk kcA)
    const int rA  = tid >> 2;          // 0..127
    const int kcA = tid & 3;
    const int c0  = (2 * kcA) ^ (rA & 7);
    const int wO0 = rA * 128 + c0 * 16;
    const int wO1 = rA * 128 + (c0 ^ 1) * 16;
    const float* aRow = values + (row0 + rA) * 1024 + kcA * 16;

    // fragment read lane offsets (bytes) — unchanged
    const int ao0 = wm * 16384 + l15 * 128 + ((lq ^ (l15 & 7)) << 4);
    const int ao1 = ao0 ^ 64;
    const int bo0 = 32768 + (wn >> 1) * 16384 + (wn & 1) * 8192
                  + l15 * 128 + ((lq ^ (l15 & 7)) << 4);
    const int bo1 = bo0 ^ 64;

    f32x4 acc[8][4];
#pragma unroll
    for (int m = 0; m < 8; ++m)
#pragma unroll
        for (int n = 0; n < 4; ++n) acc[m][n] = (f32x4)0.f;

    bf16x8 af[4][2];
    bf16x8 bf[2][2];

    auto stageB = [&](const unsigned short* s, int dOff) {
        gload16(s,             dstW + dOff);
        gload16(s + 64 * 1024, dstW + dOff + 8192);
    };
    auto readA4 = [&](int base) {
#pragma unroll
        for (int m = 0; m < 4; ++m) {
            af[m][0] = *(const bf16x8*)(lds + base + m * 2048 + ao0);
            af[m][1] = *(const bf16x8*)(lds + base + m * 2048 + ao1);
        }
    };
    auto readB2 = [&](int base) {
#pragma unroll
        for (int n = 0; n < 2; ++n) {
            bf[n][0] = *(const bf16x8*)(lds + base + n * 2048 + bo0);
            bf[n][1] = *(const bf16x8*)(lds + base + n * 2048 + bo1);
        }
    };

    float4 Pa, Pb, Pc, Pd;
    float4 Qa, Qb, Qc, Qd;
    float4 Ra, Rb, Rc, Rd;
    float4 Sa, Sb, Sc, Sd;

    // ---- prologue: kt0 A (both halves) + kt1.A0 via P (serial, one-time);
    // d0.B via gload; P left holding kt1.A1, fully landed (vmcnt 0).
    ISSUEA(Pa, Pb, Pc, Pd, 0, 0); ASM_VMCNT(0); WRITEA(Pa, Pb, Pc, Pd, 0);
    ISSUEA(Pa, Pb, Pc, Pd, 0, 1); ASM_VMCNT(0); WRITEA(Pa, Pb, Pc, Pd, 16384);
    ISSUEA(Pa, Pb, Pc, Pd, 1, 0); ASM_VMCNT(0); WRITEA(Pa, Pb, Pc, Pd, 65536);
    stageB(bSrc,          32768);
    stageB(bSrc + 131072, 49152);
    ISSUEA(Pa, Pb, Pc, Pd, 1, 1);
    ASM_VMCNT(0);                       // drain all (uniform loop entry)
    ASM_LGKM0();
    __builtin_amdgcn_s_barrier();
    __builtin_amdgcn_sched_barrier(0);

    for (int it = 0; it < 8; ++it) {
        const bool pf = (it < 7);
        // ---------- phase 0: d0, m0-3 x n0-1 ----------
        WRITEA(Pa, Pb, Pc, Pd, 81920);               // P -> d1.A1 (kt=2it+1)
        readA4(0);
        readB2(0);
        if (pf) {
            ISSUEA(Qa, Qb, Qc, Qd, 2 * it + 2, 0);
            ISSUEA(Ra, Rb, Rc, Rd, 2 * it + 2, 1);
        }
        __builtin_amdgcn_s_barrier();
        ASM_LGKM0();
        __builtin_amdgcn_s_setprio(1);
        MFMA16(0, 0);
        __builtin_amdgcn_s_setprio(0);
        __builtin_amdgcn_s_barrier();
        // ---------- phase 1: d0, m0-3 x n2-3 ----------
        readB2(2 * 2048);
        stageB(bSrc + 64, 98304);                    // d1.B0
        __builtin_amdgcn_s_barrier();
        ASM_LGKM0();
        __builtin_amdgcn_s_setprio(1);
        MFMA16(0, 2);
        __builtin_amdgcn_s_setprio(0);
        __builtin_amdgcn_s_barrier();
        // ---------- phase 2: d0, m4-7 x n2-3 ----------
        readA4(4 * 2048);
        stageB(bSrc + 64 + 131072, 114688);          // d1.B1
        __builtin_amdgcn_s_barrier();
        ASM_LGKM0();
        __builtin_amdgcn_s_setprio(1);
        MFMA16(4, 2);
        __builtin_amdgcn_s_setprio(0);
        __builtin_amdgcn_s_barrier();
        // ---------- phase 3: d0, m4-7 x n0-1 ----------
        readB2(0);
        if (pf) {
            ASM_VMCNT(8);                            // Q landed (3 phases old)
            WRITEA(Qa, Qb, Qc, Qd, 0);               // Q -> d0.A0
        }
        __builtin_amdgcn_s_barrier();
        ASM_LGKM0();
        __builtin_amdgcn_s_setprio(1);
        MFMA16(4, 0);
        __builtin_amdgcn_s_setprio(0);
        __builtin_amdgcn_sched_barrier(0);
        ASM_VMCNT(0);                                // R + d1.B landed
        __builtin_amdgcn_s_barrier();
        __builtin_amdgcn_sched_barrier(0);
        // ---------- phase 4: d1, m0-3 x n0-1 ----------
        if (pf) WRITEA(Ra, Rb, Rc, Rd, 16384);       // R -> d0.A1 (no wait)
        readA4(65536);
        readB2(65536);
        if (pf) {
            ISSUEA(Sa, Sb, Sc, Sd, 2 * it + 3, 0);
            ISSUEA(Pa, Pb, Pc, Pd, 2 * it + 3, 1);   // P' for next iter
        }
        __builtin_amdgcn_s_barrier();
        ASM_LGKM0();
        __builtin_amdgcn_s_setprio(1);
        MFMA16(0, 0);
        __builtin_amdgcn_s_setprio(0);
        __builtin_amdgcn_s_barrier();
        // ---------- phase 5: d1, m0-3 x n2-3 ----------
        readB2(65536 + 2 * 2048);
        if (pf) stageB(bSrc + 128, 32768);           // d0.B0
        __builtin_amdgcn_s_barrier();
        ASM_LGKM0();
        __builtin_amdgcn_s_setprio(1);
        MFMA16(0, 2);
        __builtin_amdgcn_s_setprio(0);
        __builtin_amdgcn_s_barrier();
        // ---------- phase 6: d1, m4-7 x n2-3 ----------
        readA4(65536 + 4 * 2048);
        if (pf) stageB(bSrc + 128 + 131072, 49152);  // d0.B1
        __builtin_amdgcn_s_barrier();
        ASM_LGKM0();
        __builtin_amdgcn_s_setprio(1);
        MFMA16(4, 2);
        __builtin_amdgcn_s_setprio(0);
        __builtin_amdgcn_s_barrier();
        // ---------- phase 7: d1, m4-7 x n0-1 ----------
        readB2(65536);
        if (pf) {
            ASM_VMCNT(8);                            // S landed (3 phases old)
            WRITEA(Sa, Sb, Sc, Sd, 65536);           // S -> d1.A0
        }
        __builtin_amdgcn_s_barrier();
        ASM_LGKM0();
        __builtin_amdgcn_s_setprio(1);
        MFMA16(4, 0);
        __builtin_amdgcn_s_setprio(0);
        __builtin_amdgcn_sched_barrier(0);
        ASM_VMCNT(0);                                // P' + d0.B landed
        __builtin_amdgcn_s_barrier();
        __builtin_amdgcn_sched_barrier(0);

        bSrc += 128;
    }

    // epilogue: score[row] += sum_u tanh(P + t[b,u]) * V[u]
    __syncthreads();
    float* fscore = (float*)lds;
    if (tid < 256) fscore[tid] = 0.f;
    __syncthreads();
    float tu[4], vu[4];
#pragma unroll
    for (int n = 0; n < 4; ++n) {
        int u = u0 + wn * 64 + n * 16 + l15;
        tu[n] = tvec[b * U_ + u];
        vu[n] = V[u];
    }
#pragma unroll
    for (int m = 0; m < 8; ++m) {
#pragma unroll
        for (int r = 0; r < 4; ++r) {
            float p = 0.f;
#pragma unroll
            for (int n = 0; n < 4; ++n) p += tanh_fast(acc[m][n][r] + tu[n]) * vu[n];
            p += __shfl_xor(p, 1);
            p += __shfl_xor(p, 2);
            p += __shfl_xor(p, 4);
            p += __shfl_xor(p, 8);
            if (l15 == 0) atomicAdd(&fscore[wm * 128 + m * 16 + lq * 4 + r], p);
        }
    }
    __syncthreads();
    if (tid < 256) atomicAdd(&scores[(size_t)b * S_ + s_local + tid], fscore[tid]);
}

// ---------------- sm_ctx_part + ctx_reduce (unchanged from R7, passed) ------
__global__ __launch_bounds__(256)
void sm_ctx_part(const float* __restrict__ scores, const float* __restrict__ values,
                 float* __restrict__ wout, float* __restrict__ ctxp) {
    const int b   = blockIdx.x;
    const int sc  = blockIdx.y;
    const int tid = threadIdx.x;
    __shared__ float red[256];
    __shared__ float ws_[128];

    float v[8];
    float m = -1e30f;
#pragma unroll
    for (int i = 0; i < 8; ++i) {
        v[i] = scores[(size_t)b * S_ + tid + i * 256];
        m = fmaxf(m, v[i]);
    }
    red[tid] = m; __syncthreads();
    for (int off = 128; off > 0; off >>= 1) {
        if (tid < off) red[tid] = fmaxf(red[tid], red[tid + off]);
        __syncthreads();
    }
    m = red[0];
    __syncthreads();
    float s = 0.f;
#pragma unroll
    for (int i = 0; i < 8; ++i) s += __expf(v[i] - m);
    red[tid] = s; __syncthreads();
    for (int off = 128; off > 0; off >>= 1) {
        if (tid < off) red[tid] += red[tid + off];
        __syncthreads();
    }
    float inv = 1.f / red[0];
    __syncthreads();

    if (tid < 128) {
        float x = scores[(size_t)b * S_ + sc * 128 + tid];
        float w = __expf(x - m) * inv;
        ws_[tid] = w;
        wout[(size_t)b * S_ + sc * 128 + tid] = w;
    }
    __syncthreads();

    const float4* vp = (const float4*)(values + ((size_t)b * S_ + sc * 128) * DV) + tid;
    float ax = 0.f, ay = 0.f, az = 0.f, aw = 0.f;
#pragma unroll 4
    for (int s2 = 0; s2 < 128; ++s2) {
        float4 vv = vp[(size_t)s2 * 256];
        float wv = ws_[s2];
        ax += wv * vv.x; ay += wv * vv.y; az += wv * vv.z; aw += wv * vv.w;
    }
    float4 outv; outv.x = ax; outv.y = ay; outv.z = az; outv.w = aw;
    *(float4*)(ctxp + ((size_t)(b * 16 + sc)) * 1024 + tid * 4) = outv;
}

__global__ __launch_bounds__(256)
void ctx_reduce(const float* __restrict__ ctxp, float* __restrict__ ctx) {
    const int b  = blockIdx.x;
    const int dq = blockIdx.y;
    const int d  = dq * 256 + threadIdx.x;
    const float* p = ctxp + (size_t)b * 16 * 1024 + d;
    float s = 0.f;
#pragma unroll
    for (int sc = 0; sc < 16; ++sc) s += p[sc * 1024];
    ctx[b * DV + d] = s;
}

// ================= legacy kernels (low ws fallback path) ====================
__global__ void init_kernel(const float* __restrict__ b1, const float* __restrict__ b2,
                            float* __restrict__ t, float* __restrict__ ctx,
                            float* __restrict__ scores) {
    int i = blockIdx.x * 256 + threadIdx.x;
    scores[i] = 0.f;
    if (i < B_ * U_) {
        int u = i & (U_ - 1);
        t[i]   = b1[u] + b2[u];
        ctx[i] = 0.f;
    }
}

__global__ void projq_kernel(const float* __restrict__ q, const float* __restrict__ W2,
                             float* __restrict__ t) {
    int b  = blockIdx.x;
    int ks = blockIdx.y;
    int tid = threadIdx.x;
    __shared__ float qs[64];
    if (tid < 64) qs[tid] = q[b * DV + ks * 64 + tid];
    __syncthreads();
    float a0 = 0.f, a1 = 0.f, a2 = 0.f, a3 = 0.f;
    const float* w = W2 + (size_t)(ks * 64) * U_;
    for (int d = 0; d < 64; ++d) {
        float qd = qs[d];
        const float* wr = w + (size_t)d * U_ + tid;
        a0 += qd * wr[0];
        a1 += qd * wr[256];
        a2 += qd * wr[512];
        a3 += qd * wr[768];
    }
    atomicAdd(&t[b * U_ + tid      ], a0);
    atomicAdd(&t[b * U_ + tid + 256], a1);
    atomicAdd(&t[b * U_ + tid + 512], a2);
    atomicAdd(&t[b * U_ + tid + 768], a3);
}

__launch_bounds__(256, 2)
__global__ void scores_vec(const float* __restrict__ values, const float* __restrict__ W1,
                           const float* __restrict__ t, const float* __restrict__ V,
                           float* __restrict__ scores) {
    __shared__ float vA[16][132];
    __shared__ float vB[16][68];
    __shared__ float fscore[128];
    const int b   = blockIdx.y;
    const int s0  = blockIdx.x * 128;
    const int tid = threadIdx.x;
    const int tx  = tid & 15, ty = tid >> 4;
    if (tid < 128) fscore[tid] = 0.f;
    const float* vbase = values + ((size_t)b * S_ + s0) * (size_t)DV;
    const int lm = tid >> 2, lkq = (tid & 3) * 4;
    const int lbk = tid >> 4, lbj = (tid & 15) * 4;
    for (int nt = 0; nt < U_ / 64; ++nt) {
        const int u0 = nt * 64;
        float acc[8][4];
#pragma unroll
        for (int i = 0; i < 8; ++i)
#pragma unroll
            for (int j = 0; j < 4; ++j) acc[i][j] = 0.f;
        for (int k0 = 0; k0 < DV; k0 += 16) {
            __syncthreads();
            const float4 v0 = *(const float4*)(vbase + (size_t)lm * DV + k0 + lkq);
            const float4 v1 = *(const float4*)(vbase + (size_t)(lm + 64) * DV + k0 + lkq);
            vA[lkq + 0][lm] = v0.x; vA[lkq + 1][lm] = v0.y;
            vA[lkq + 2][lm] = v0.z; vA[lkq + 3][lm] = v0.w;
            vA[lkq + 0][lm + 64] = v1.x; vA[lkq + 1][lm + 64] = v1.y;
            vA[lkq + 2][lm + 64] = v1.z; vA[lkq + 3][lm + 64] = v1.w;
            *(float4*)&vB[lbk][lbj] = *(const float4*)(W1 + (size_t)(k0 + lbk) * U_ + u0 + lbj);
            __syncthreads();
#pragma unroll
            for (int k = 0; k < 16; ++k) {
                float4 va0 = *(const float4*)&vA[k][ty * 8];
                float4 va1 = *(const float4*)&vA[k][ty * 8 + 4];
                float4 vb  = *(const float4*)&vB[k][tx * 4];
                float a_[8] = {va0.x, va0.y, va0.z, va0.w, va1.x, va1.y, va1.z, va1.w};
                float b_[4] = {vb.x, vb.y, vb.z, vb.w};
#pragma unroll
                for (int i = 0; i < 8; ++i)
#pragma unroll
                    for (int j = 0; j < 4; ++j) acc[i][j] += a_[i] * b_[j];
            }
        }
        float tq[4], vv[4];
#pragma unroll
        for (int j = 0; j < 4; ++j) {
            int u = u0 + tx * 4 + j;
            tq[j] = t[b * U_ + u];
            vv[j] = V[u];
        }
#pragma unroll
        for (int i = 0; i < 8; ++i) {
            float p = 0.f;
#pragma unroll
            for (int j = 0; j < 4; ++j) p += tanhf(acc[i][j] + tq[j]) * vv[j];
            p += __shfl_down(p, 8, 16);
            p += __shfl_down(p, 4, 16);
            p += __shfl_down(p, 2, 16);
            p += __shfl_down(p, 1, 16);
            if (tx == 0) fscore[ty * 8 + i] += p;
        }
    }
    __syncthreads();
    if (tid < 128) scores[(size_t)b * S_ + s0 + tid] = fscore[tid];
}

__global__ void softmax_kernel(const float* __restrict__ scores, float* __restrict__ wout) {
    int b = blockIdx.x;
    int tid = threadIdx.x;
    __shared__ float red[256];
    float v[8];
    float m = -1e30f;
#pragma unroll
    for (int i = 0; i < 8; ++i) {
        v[i] = scores[(size_t)b * S_ + tid + i * 256];
        m = fmaxf(m, v[i]);
    }
    red[tid] = m; __syncthreads();
    for (int off = 128; off > 0; off >>= 1) {
        if (tid < off) red[tid] = fmaxf(red[tid], red[tid + off]);
        __syncthreads();
    }
    m = red[0];
    __syncthreads();
    float s = 0.f;
#pragma unroll
    for (int i = 0; i < 8; ++i) { v[i] = __expf(v[i] - m); s += v[i]; }
    red[tid] = s; __syncthreads();
    for (int off = 128; off > 0; off >>= 1) {
        if (tid < off) red[tid] += red[tid + off];
        __syncthreads();
    }
    float inv = 1.f / red[0];
#pragma unroll
    for (int i = 0; i < 8; ++i) wout[(size_t)b * S_ + tid + i * 256] = v[i] * inv;
}

__global__ void context_kernel(const float* __restrict__ values, const float* __restrict__ w,
                               float* __restrict__ ctx) {
    int b   = blockIdx.x;
    int sc  = blockIdx.y;
    int tid = threadIdx.x;
    __shared__ float ws_[128];
    if (tid < 128) ws_[tid] = w[(size_t)b * S_ + sc * 128 + tid];
    __syncthreads();
    const float4* vp = (const float4*)(values + ((size_t)b * S_ + sc * 128) * DV) + tid;
    float ax = 0.f, ay = 0.f, az = 0.f, aw = 0.f;
#pragma unroll 4
    for (int s = 0; s < 128; ++s) {
        float4 v = vp[(size_t)s * 256];
        float wv = ws_[s];
        ax += wv * v.x; ay += wv * v.y; az += wv * v.z; aw += wv * v.w;
    }
    float* c = ctx + b * DV + tid * 4;
    atomicAdd(c + 0, ax); atomicAdd(c + 1, ay);
    atomicAdd(c + 2, az); atomicAdd(c + 3, aw);
}

// ---------------- launch ----------------------------------------------------
extern "C" void kernel_launch(void* const* d_in, const int* in_sizes, int n_in,
                              void* d_out, int out_size, void* d_ws, size_t ws_size,
                              hipStream_t stream) {
    const float* query  = (const float*)d_in[0];
    const float* values = (const float*)d_in[1];
    const float* W1     = (const float*)d_in[2];
    const float* b1     = (const float*)d_in[3];
    const float* W2     = (const float*)d_in[4];
    const float* b2     = (const float*)d_in[5];
    const float* V      = (const float*)d_in[6];
    // bV (d_in[7]) shifts all scores equally -> softmax-invariant.

    float* out  = (float*)d_out;
    float* ctx  = out;                 // [32, 1024]
    float* wout = out + B_ * DV;       // [32, 2048]

    char* ws = (char*)d_ws;
    const size_t W1T_BYTES  = (size_t)U_ * DV * 2;             // 2 MB
    const size_t T_BYTES    = (size_t)B_ * U_ * 4;             // 128 KB
    const size_t SC_BYTES   = (size_t)B_ * S_ * 4;             // 256 KB
    const size_t CTXP_BYTES = (size_t)B_ * 16 * DV * 4;        // 2 MB

    if (ws_size >= W1T_BYTES + T_BYTES + SC_BYTES + CTXP_BYTES) {
        // fast path: 4 launches, NO cvt pass, ws = 4.4 MB.
        unsigned short* W1T = (unsigned short*)ws;
        float* t      = (float*)(ws + W1T_BYTES);
        float* scores = t + B_ * U_;
        float* ctxp   = scores + B_ * S_;

        prep_small   <<<dim3(640),    256, 0, stream>>>(W1, W1T, query, W2,
                                                        b1, b2, t, scores);
        scores_mfma8g<<<dim3(1024),   512, 0, stream>>>(values, W1T, t, V, scores);
        sm_ctx_part  <<<dim3(32, 16), 256, 0, stream>>>(scores, values, wout, ctxp);
        ctx_reduce   <<<dim3(32, 4),  256, 0, stream>>>(ctxp, ctx);
    } else {
        // low path: round-1 fp32 vector kernel (384 KB ws, proven)
        float* t      = (float*)ws;
        float* scores = t + B_ * U_;

        init_kernel   <<<dim3(256),      256, 0, stream>>>(b1, b2, t, ctx, scores);
        projq_kernel  <<<dim3(32, 16),   256, 0, stream>>>(query, W2, t);
        scores_vec    <<<dim3(16, 32),   256, 0, stream>>>(values, W1, t, V, scores);
        softmax_kernel<<<dim3(32),       256, 0, stream>>>(scores, wout);
        context_kernel<<<dim3(32, 16),   256, 0, stream>>>(values, wout, ctx);
    }
}

// Round 9
// 623.315 us; speedup vs baseline: 1.0822x; 1.0376x over previous
//
#include <hip/hip_runtime.h>
#include <math.h>

#define B_  32
#define S_  2048
#define DV  1024
#define U_  1024

typedef __attribute__((ext_vector_type(8))) short bf16x8;
typedef __attribute__((ext_vector_type(4))) float f32x4;

__device__ inline unsigned short f2bf(float f) {
    unsigned int x = __float_as_uint(f);
    return (unsigned short)((x + 0x7fffu + ((x >> 16) & 1u)) >> 16);
}

__device__ inline uint4 pack8(float4 a, float4 b) {
    union { unsigned short s[8]; uint4 u; } p;
    p.s[0] = f2bf(a.x); p.s[1] = f2bf(a.y); p.s[2] = f2bf(a.z); p.s[3] = f2bf(a.w);
    p.s[4] = f2bf(b.x); p.s[5] = f2bf(b.y); p.s[6] = f2bf(b.z); p.s[7] = f2bf(b.w);
    return p.u;
}

__device__ inline float tanh_fast(float x) {
    float ax = fabsf(x);
    float e  = __expf(ax + ax);
    float t  = 1.0f - __fdividef(2.0f, e + 1.0f);
    return copysignf(t, x);
}

// async global->LDS, 16B per lane; LDS dest is the wave-uniform base.
__device__ __forceinline__ void gload16(const void* g, void* l) {
    __builtin_amdgcn_global_load_lds(
        (const __attribute__((address_space(1))) void*)g,
        (__attribute__((address_space(3))) void*)l,
        16, 0, 0);
}

#define ASM_VMCNT(N) asm volatile("s_waitcnt vmcnt(" #N ")" ::: "memory")
#define ASM_LGKM0()  do { asm volatile("s_waitcnt lgkmcnt(0)" ::: "memory"); \
                          __builtin_amdgcn_sched_barrier(0); } while (0)

// ---------------- K0: t[b,u] = b1[u]+b2[u]; zero ctx + scores ---------------
__global__ void init_kernel(const float* __restrict__ b1, const float* __restrict__ b2,
                            float* __restrict__ t, float* __restrict__ ctx,
                            float* __restrict__ scores) {
    int i = blockIdx.x * 256 + threadIdx.x;   // 65536
    scores[i] = 0.f;
    if (i < B_ * U_) {
        int u = i & (U_ - 1);
        t[i]   = b1[u] + b2[u];
        ctx[i] = 0.f;
    }
}

// ---------------- K1: t[b,u] += query[b,:] @ W2[:,u] ------------------------
__global__ void projq_kernel(const float* __restrict__ q, const float* __restrict__ W2,
                             float* __restrict__ t) {
    int b  = blockIdx.x;        // 32
    int ks = blockIdx.y;        // 16 chunks of 64 k-rows
    int tid = threadIdx.x;
    __shared__ float qs[64];
    if (tid < 64) qs[tid] = q[b * DV + ks * 64 + tid];
    __syncthreads();
    float a0 = 0.f, a1 = 0.f, a2 = 0.f, a3 = 0.f;
    const float* w = W2 + (size_t)(ks * 64) * U_;
    for (int d = 0; d < 64; ++d) {
        float qd = qs[d];
        const float* wr = w + (size_t)d * U_ + tid;
        a0 += qd * wr[0];
        a1 += qd * wr[256];
        a2 += qd * wr[512];
        a3 += qd * wr[768];
    }
    atomicAdd(&t[b * U_ + tid      ], a0);
    atomicAdd(&t[b * U_ + tid + 256], a1);
    atomicAdd(&t[b * U_ + tid + 512], a2);
    atomicAdd(&t[b * U_ + tid + 768], a3);
}

// ---------------- cvt_lds: values fp32 -> K-tiled bf16 via LDS bounce -------
// Output byte-image IDENTICAL to R4/R5's tiled layout (consumed unchanged by
// scores_mfma8):  dst = stile*512KB + kt*32KB + h*16KB + r*128 + pchunk*16,
// pchunk = (kk>>3) ^ (r&7).
// Both sides coalesced: block (stile, g) handles 16 rows.
//   stage: 8 passes x 2 rows; wave reads 2 KB CONTIGUOUS fp32 per pass;
//          scatter lands in LDS only (kt-stride 2112 B: bank-phase split).
//   flush: 8 passes x 2 kt-slices; wave writes 1 KB CONTIGUOUS global.
__global__ __launch_bounds__(256)
void cvt_lds(const float* __restrict__ v, char* __restrict__ o) {
    __shared__ __align__(16) char sm[16 * 2112];   // 33 KB
    const int stile = blockIdx.x;      // 256
    const int g     = blockIdx.y;      // 16 row-groups of 16
    const int t     = threadIdx.x;
    const int tl    = t & 127;
    const int th    = t >> 7;          // 0..1
    const int kt    = tl >> 3;         // 0..15
    const int kch   = tl & 7;          // k-chunk within 64-k tile
    const int rowg  = stile * 256 + g * 16;
    const int h     = g >> 3;
    const int rbase = (g & 7) * 16;    // r = rbase + local, rbase % 16 == 0
#pragma unroll
    for (int p = 0; p < 8; ++p) {
        int local = p * 2 + th;
        const float4* src = (const float4*)(v + (size_t)(rowg + local) * 1024 + tl * 8);
        float4 f0 = src[0], f1 = src[1];
        int pchunk = kch ^ (local & 7);            // r&7 == local&7 (rbase%16==0)
        *(uint4*)(sm + kt * 2112 + local * 128 + pchunk * 16) = pack8(f0, f1);
    }
    __syncthreads();
#pragma unroll
    for (int q = 0; q < 8; ++q) {
        int kt2 = q * 2 + th;
        uint4 w = *(const uint4*)(sm + kt2 * 2112 + tl * 16);
        *(uint4*)(o + (size_t)stile * 524288 + kt2 * 32768 + h * 16384
                  + rbase * 128 + tl * 16) = w;
    }
}

// ---------------- prep: W1 [k][u] fp32 -> W1T [u][k] bf16 -------------------
__global__ void prep_w1t(const float* __restrict__ W1, unsigned short* __restrict__ W1T) {
    __shared__ float tile[64][65];
    int k0 = blockIdx.x * 64, u0 = blockIdx.y * 64;
    int t = threadIdx.x;
    int lr = t >> 4, lc = (t & 15) * 4;
#pragma unroll
    for (int i = 0; i < 4; ++i) {
        float4 f = *(const float4*)&W1[(size_t)(k0 + lr + i * 16) * U_ + u0 + lc];
        tile[lr + i * 16][lc + 0] = f.x; tile[lr + i * 16][lc + 1] = f.y;
        tile[lr + i * 16][lc + 2] = f.z; tile[lr + i * 16][lc + 3] = f.w;
    }
    __syncthreads();
    int ur = t >> 2, kq = (t & 3) * 16;
    union { unsigned short s[8]; uint4 u; } p0, p1;
#pragma unroll
    for (int e = 0; e < 8; ++e) p0.s[e] = f2bf(tile[kq + e][ur]);
#pragma unroll
    for (int e = 0; e < 8; ++e) p1.s[e] = f2bf(tile[kq + 8 + e][ur]);
    unsigned short* dst = W1T + (size_t)(u0 + ur) * 1024 + k0 + kq;
    *(uint4*)dst       = p0.u;
    *(uint4*)(dst + 8) = p1.u;
}

// ---------------- K2: 256x256 tile, BK=64, 8-phase, TILED A source ----------
// (verbatim R4/R5/R7 kernel — proven 170-174 us, numerics verified)
#define MFMA16(MB, NB)                                                          \
    _Pragma("unroll") for (int ks = 0; ks < 2; ++ks)                            \
    _Pragma("unroll") for (int n = 0; n < 2; ++n)                               \
    _Pragma("unroll") for (int m = 0; m < 4; ++m)                               \
        acc[(MB)+m][(NB)+n] = __builtin_amdgcn_mfma_f32_16x16x32_bf16(          \
            af[m][ks], bf[n][ks], acc[(MB)+m][(NB)+n], 0, 0, 0);

__launch_bounds__(512, 2)
__global__ void scores_mfma8(const char* __restrict__ AbfT,
                             const unsigned short* __restrict__ W1T,
                             const float* __restrict__ tvec,
                             const float* __restrict__ V,
                             float* __restrict__ scores) {
    __shared__ __align__(16) char lds[131072];   // 128 KB

    const int tid  = threadIdx.x;
    const int lane = tid & 63;
    const int wave = tid >> 6;        // 0..7
    const int wm   = wave >> 2;       // 0..1  (row half of 256)
    const int wn   = wave & 3;        // 0..3  (64-col strip of 256)
    const int l15  = lane & 15;
    const int lq   = lane >> 4;       // 0..3

    const int id    = blockIdx.x;
    const int wg    = (id & 7) * 128 + (id >> 3);
    const int utile = wg & 3;                    // 4 u-tiles of 256
    const int stile = wg >> 2;                   // 256 s-tiles of 256
    const size_t row0 = (size_t)stile * 256;
    const int b       = (int)(row0 >> 11);
    const int s_local = (int)(row0 & 2047);
    const int u0      = utile * 256;

    const char* aBase = AbfT + (size_t)stile * 524288 + wave * 1024 + lane * 16;
    const int rowst = wave * 8 + (lane >> 3);
    const int kch8  = ((lane & 7) ^ ((lane >> 3) & 7)) * 8;
    const unsigned short* bSrc = W1T + (size_t)(u0 + rowst) * 1024 + kch8;
    char* const dstW = lds + wave * 1024;

    const int ao0 = wm * 16384 + l15 * 128 + ((lq ^ (l15 & 7)) << 4);
    const int ao1 = ao0 ^ 64;
    const int bo0 = 32768 + (wn >> 1) * 16384 + (wn & 1) * 8192
                  + l15 * 128 + ((lq ^ (l15 & 7)) << 4);
    const int bo1 = bo0 ^ 64;

    f32x4 acc[8][4];
#pragma unroll
    for (int m = 0; m < 8; ++m)
#pragma unroll
        for (int n = 0; n < 4; ++n) acc[m][n] = (f32x4)0.f;

    bf16x8 af[4][2];
    bf16x8 bf[2][2];

    auto stageA = [&](size_t gOff, int dOff) {
        gload16(aBase + gOff,        dstW + dOff);
        gload16(aBase + gOff + 8192, dstW + dOff + 8192);
    };
    auto stageB = [&](const unsigned short* s, int dOff) {
        gload16(s,             dstW + dOff);
        gload16(s + 64 * 1024, dstW + dOff + 8192);
    };
    auto readA4 = [&](int base) {
#pragma unroll
        for (int m = 0; m < 4; ++m) {
            af[m][0] = *(const bf16x8*)(lds + base + m * 2048 + ao0);
            af[m][1] = *(const bf16x8*)(lds + base + m * 2048 + ao1);
        }
    };
    auto readB2 = [&](int base) {
#pragma unroll
        for (int n = 0; n < 2; ++n) {
            bf[n][0] = *(const bf16x8*)(lds + base + n * 2048 + bo0);
            bf[n][1] = *(const bf16x8*)(lds + base + n * 2048 + bo1);
        }
    };

    stageA(0,     0);
    stageA(16384, 16384);
    stageB(bSrc,          32768);
    stageB(bSrc + 131072, 49152);
    stageA(32768, 65536);
    __builtin_amdgcn_sched_barrier(0);
    ASM_VMCNT(2);
    __builtin_amdgcn_s_barrier();
    __builtin_amdgcn_sched_barrier(0);

    for (int it = 0; it < 8; ++it) {
        const bool pf = (it < 7);
        const size_t aIt = (size_t)it * 65536;
        // ---------- phase 0: d0, m0-3 x n0-1 ----------
        readA4(0);
        readB2(0);
        stageA(aIt + 49152, 81920);                  // A1(kt1) -> d1
        __builtin_amdgcn_s_barrier();
        ASM_LGKM0();
        __builtin_amdgcn_s_setprio(1);
        MFMA16(0, 0);
        __builtin_amdgcn_s_setprio(0);
        __builtin_amdgcn_s_barrier();
        // ---------- phase 1: d0, m0-3 x n2-3 ----------
        readB2(2 * 2048);
        stageB(bSrc + 64, 98304);                    // B0(kt1) -> d1
        __builtin_amdgcn_s_barrier();
        ASM_LGKM0();
        __builtin_amdgcn_s_setprio(1);
        MFMA16(0, 2);
        __builtin_amdgcn_s_setprio(0);
        __builtin_amdgcn_s_barrier();
        // ---------- phase 2: d0, m4-7 x n2-3 ----------
        readA4(4 * 2048);
        stageB(bSrc + 64 + 131072, 114688);          // B1(kt1) -> d1
        __builtin_amdgcn_s_barrier();
        ASM_LGKM0();
        __builtin_amdgcn_s_setprio(1);
        MFMA16(4, 2);
        __builtin_amdgcn_s_setprio(0);
        __builtin_amdgcn_s_barrier();
        // ---------- phase 3: d0, m4-7 x n0-1 ----------
        readB2(0);
        if (pf) stageA(aIt + 65536, 0);              // A0(kt2) -> d0
        __builtin_amdgcn_s_barrier();
        ASM_LGKM0();
        __builtin_amdgcn_s_setprio(1);
        MFMA16(4, 0);
        __builtin_amdgcn_s_setprio(0);
        __builtin_amdgcn_sched_barrier(0);
        if (pf) { ASM_VMCNT(2); } else { ASM_VMCNT(0); }   // d1 (kt1) landed
        __builtin_amdgcn_s_barrier();
        __builtin_amdgcn_sched_barrier(0);
        // ---------- phase 4: d1, m0-3 x n0-1 ----------
        readA4(65536);
        readB2(65536);
        if (pf) stageA(aIt + 81920, 16384);          // A1(kt2) -> d0
        __builtin_amdgcn_s_barrier();
        ASM_LGKM0();
        __builtin_amdgcn_s_setprio(1);
        MFMA16(0, 0);
        __builtin_amdgcn_s_setprio(0);
        __builtin_amdgcn_s_barrier();
        // ---------- phase 5: d1, m0-3 x n2-3 ----------
        readB2(65536 + 2 * 2048);
        if (pf) stageB(bSrc + 128, 32768);           // B0(kt2) -> d0
        __builtin_amdgcn_s_barrier();
        ASM_LGKM0();
        __builtin_amdgcn_s_setprio(1);
        MFMA16(0, 2);
        __builtin_amdgcn_s_setprio(0);
        __builtin_amdgcn_s_barrier();
        // ---------- phase 6: d1, m4-7 x n2-3 ----------
        if (pf) stageB(bSrc + 128 + 131072, 49152);  // B1(kt2) -> d0
        readA4(65536 + 4 * 2048);
        __builtin_amdgcn_s_barrier();
        ASM_LGKM0();
        __builtin_amdgcn_s_setprio(1);
        MFMA16(4, 2);
        __builtin_amdgcn_s_setprio(0);
        __builtin_amdgcn_s_barrier();
        // ---------- phase 7: d1, m4-7 x n0-1 ----------
        readB2(65536);
        if (pf) stageA(aIt + 98304, 65536);          // A0(kt3) -> d1
        __builtin_amdgcn_s_barrier();
        ASM_LGKM0();
        __builtin_amdgcn_s_setprio(1);
        MFMA16(4, 0);
        __builtin_amdgcn_s_setprio(0);
        __builtin_amdgcn_sched_barrier(0);
        if (pf) { ASM_VMCNT(2); }                    // d0 (kt2) landed
        __builtin_amdgcn_s_barrier();
        __builtin_amdgcn_sched_barrier(0);

        bSrc += 128;
    }

    // epilogue: score[row] += sum_u tanh(P + t[b,u]) * V[u]
    __syncthreads();
    float* fscore = (float*)lds;
    if (tid < 256) fscore[tid] = 0.f;
    __syncthreads();
    float tu[4], vu[4];
#pragma unroll
    for (int n = 0; n < 4; ++n) {
        int u = u0 + wn * 64 + n * 16 + l15;
        tu[n] = tvec[b * U_ + u];
        vu[n] = V[u];
    }
#pragma unroll
    for (int m = 0; m < 8; ++m) {
#pragma unroll
        for (int r = 0; r < 4; ++r) {
            float p = 0.f;
#pragma unroll
            for (int n = 0; n < 4; ++n) p += tanh_fast(acc[m][n][r] + tu[n]) * vu[n];
            p += __shfl_xor(p, 1);
            p += __shfl_xor(p, 2);
            p += __shfl_xor(p, 4);
            p += __shfl_xor(p, 8);
            if (l15 == 0) atomicAdd(&fscore[wm * 128 + m * 16 + lq * 4 + r], p);
        }
    }
    __syncthreads();
    if (tid < 256) atomicAdd(&scores[(size_t)b * S_ + s_local + tid], fscore[tid]);
}

// ---------------- K2 (legacy): MFMA scores GEMM, reg-staged (mid path) ------
template<bool ABF16>
__launch_bounds__(256, 2)
__global__ void scores_mfma(const void* __restrict__ aPtr,
                            const unsigned short* __restrict__ W1T,
                            const float* __restrict__ t,
                            const float* __restrict__ V,
                            float* __restrict__ scores) {
    __shared__ unsigned short sA[128 * 40];
    __shared__ unsigned short sB[256 * 40];
    __shared__ float fscore[128];

    const int tid  = threadIdx.x;
    const int lane = tid & 63;
    const int wave = tid >> 6;
    const int wm = wave & 1, wn = wave >> 1;
    const int l15 = lane & 15, lq = lane >> 4;

    const int id    = blockIdx.x;
    const int utile = (id >> 3) & 3;
    const int stile = (id & 7) | ((id >> 5) << 3);
    const size_t row0 = (size_t)stile * 128;
    const int b       = (int)(row0 >> 11);
    const int s_local = (int)(row0 & 2047);
    const int u0      = utile * 256;

    if (tid < 128) fscore[tid] = 0.f;

    const int ar = tid >> 1, ak = (tid & 1) << 4;
    const int br = tid >> 1, bk = (tid & 1) << 4;

    const float* Af = (const float*)aPtr + (row0 + ar) * 1024 + ak;
    const unsigned short* Ab = (const unsigned short*)aPtr + (row0 + ar) * 1024 + ak;
    const unsigned short* Bp0 = W1T + (size_t)(u0 + br) * 1024 + bk;
    const unsigned short* Bp1 = Bp0 + 128 * 1024;

    f32x4 acc[4][8];
#pragma unroll
    for (int i = 0; i < 4; ++i)
#pragma unroll
        for (int j = 0; j < 8; ++j) acc[i][j] = (f32x4)0.f;

    uint4 sa0, sa1, sb0, sb1, sb2, sb3;
    float4 fa0, fa1, fa2, fa3;

    if (ABF16) {
        sa0 = *(const uint4*)(Ab);
        sa1 = *(const uint4*)(Ab + 8);
    } else {
        fa0 = *(const float4*)(Af);
        fa1 = *(const float4*)(Af + 4);
        fa2 = *(const float4*)(Af + 8);
        fa3 = *(const float4*)(Af + 12);
    }
    sb0 = *(const uint4*)(Bp0);
    sb1 = *(const uint4*)(Bp0 + 8);
    sb2 = *(const uint4*)(Bp1);
    sb3 = *(const uint4*)(Bp1 + 8);

    for (int k0 = 0; k0 < 1024; k0 += 32) {
        __syncthreads();
        if (ABF16) {
            *(uint4*)&sA[ar * 40 + ak]     = sa0;
            *(uint4*)&sA[ar * 40 + ak + 8] = sa1;
        } else {
            union { unsigned short s[8]; uint4 u; } p0, p1;
            p0.s[0] = f2bf(fa0.x); p0.s[1] = f2bf(fa0.y); p0.s[2] = f2bf(fa0.z); p0.s[3] = f2bf(fa0.w);
            p0.s[4] = f2bf(fa1.x); p0.s[5] = f2bf(fa1.y); p0.s[6] = f2bf(fa1.z); p0.s[7] = f2bf(fa1.w);
            p1.s[0] = f2bf(fa2.x); p1.s[1] = f2bf(fa2.y); p1.s[2] = f2bf(fa2.z); p1.s[3] = f2bf(fa2.w);
            p1.s[4] = f2bf(fa3.x); p1.s[5] = f2bf(fa3.y); p1.s[6] = f2bf(fa3.z); p1.s[7] = f2bf(fa3.w);
            *(uint4*)&sA[ar * 40 + ak]     = p0.u;
            *(uint4*)&sA[ar * 40 + ak + 8] = p1.u;
        }
        *(uint4*)&sB[br * 40 + bk]           = sb0;
        *(uint4*)&sB[br * 40 + bk + 8]       = sb1;
        *(uint4*)&sB[(br + 128) * 40 + bk]     = sb2;
        *(uint4*)&sB[(br + 128) * 40 + bk + 8] = sb3;

        if (k0 + 32 < 1024) {
            int nk = k0 + 32;
            if (ABF16) {
                sa0 = *(const uint4*)(Ab + nk);
                sa1 = *(const uint4*)(Ab + nk + 8);
            } else {
                fa0 = *(const float4*)(Af + nk);
                fa1 = *(const float4*)(Af + nk + 4);
                fa2 = *(const float4*)(Af + nk + 8);
                fa3 = *(const float4*)(Af + nk + 12);
            }
            sb0 = *(const uint4*)(Bp0 + nk);
            sb1 = *(const uint4*)(Bp0 + nk + 8);
            sb2 = *(const uint4*)(Bp1 + nk);
            sb3 = *(const uint4*)(Bp1 + nk + 8);
        }
        __syncthreads();

        bf16x8 af[4];
#pragma unroll
        for (int i = 0; i < 4; ++i)
            af[i] = *(const bf16x8*)&sA[(64 * wm + 16 * i + l15) * 40 + lq * 8];
#pragma unroll
        for (int j = 0; j < 8; ++j) {
            bf16x8 bfj = *(const bf16x8*)&sB[(128 * wn + 16 * j + l15) * 40 + lq * 8];
#pragma unroll
            for (int i = 0; i < 4; ++i)
                acc[i][j] = __builtin_amdgcn_mfma_f32_16x16x32_bf16(af[i], bfj, acc[i][j], 0, 0, 0);
        }
    }

    float tu[8], vu[8];
#pragma unroll
    for (int j = 0; j < 8; ++j) {
        int u = u0 + 128 * wn + 16 * j + l15;
        tu[j] = t[b * U_ + u];
        vu[j] = V[u];
    }
#pragma unroll
    for (int i = 0; i < 4; ++i) {
#pragma unroll
        for (int r = 0; r < 4; ++r) {
            float p = 0.f;
#pragma unroll
            for (int j = 0; j < 8; ++j) p += tanh_fast(acc[i][j][r] + tu[j]) * vu[j];
            p += __shfl_xor(p, 1);
            p += __shfl_xor(p, 2);
            p += __shfl_xor(p, 4);
            p += __shfl_xor(p, 8);
            if (l15 == 0) atomicAdd(&fscore[64 * wm + 16 * i + lq * 4 + r], p);
        }
    }
    __syncthreads();
    if (tid < 128) atomicAdd(&scores[(size_t)b * S_ + s_local + tid], fscore[tid]);
}

// ---------------- K2-low: fp32 vector scores (last-resort ws fallback) ------
__launch_bounds__(256, 2)
__global__ void scores_vec(const float* __restrict__ values, const float* __restrict__ W1,
                           const float* __restrict__ t, const float* __restrict__ V,
                           float* __restrict__ scores) {
    __shared__ float vA[16][132];
    __shared__ float vB[16][68];
    __shared__ float fscore[128];
    const int b   = blockIdx.y;
    const int s0  = blockIdx.x * 128;
    const int tid = threadIdx.x;
    const int tx  = tid & 15, ty = tid >> 4;
    if (tid < 128) fscore[tid] = 0.f;
    const float* vbase = values + ((size_t)b * S_ + s0) * (size_t)DV;
    const int lm = tid >> 2, lkq = (tid & 3) * 4;
    const int lbk = tid >> 4, lbj = (tid & 15) * 4;
    for (int nt = 0; nt < U_ / 64; ++nt) {
        const int u0 = nt * 64;
        float acc[8][4];
#pragma unroll
        for (int i = 0; i < 8; ++i)
#pragma unroll
            for (int j = 0; j < 4; ++j) acc[i][j] = 0.f;
        for (int k0 = 0; k0 < DV; k0 += 16) {
            __syncthreads();
            const float4 v0 = *(const float4*)(vbase + (size_t)lm * DV + k0 + lkq);
            const float4 v1 = *(const float4*)(vbase + (size_t)(lm + 64) * DV + k0 + lkq);
            vA[lkq + 0][lm] = v0.x; vA[lkq + 1][lm] = v0.y;
            vA[lkq + 2][lm] = v0.z; vA[lkq + 3][lm] = v0.w;
            vA[lkq + 0][lm + 64] = v1.x; vA[lkq + 1][lm + 64] = v1.y;
            vA[lkq + 2][lm + 64] = v1.z; vA[lkq + 3][lm + 64] = v1.w;
            *(float4*)&vB[lbk][lbj] = *(const float4*)(W1 + (size_t)(k0 + lbk) * U_ + u0 + lbj);
            __syncthreads();
#pragma unroll
            for (int k = 0; k < 16; ++k) {
                float4 va0 = *(const float4*)&vA[k][ty * 8];
                float4 va1 = *(const float4*)&vA[k][ty * 8 + 4];
                float4 vb  = *(const float4*)&vB[k][tx * 4];
                float a_[8] = {va0.x, va0.y, va0.z, va0.w, va1.x, va1.y, va1.z, va1.w};
                float b_[4] = {vb.x, vb.y, vb.z, vb.w};
#pragma unroll
                for (int i = 0; i < 8; ++i)
#pragma unroll
                    for (int j = 0; j < 4; ++j) acc[i][j] += a_[i] * b_[j];
            }
        }
        float tq[4], vv[4];
#pragma unroll
        for (int j = 0; j < 4; ++j) {
            int u = u0 + tx * 4 + j;
            tq[j] = t[b * U_ + u];
            vv[j] = V[u];
        }
#pragma unroll
        for (int i = 0; i < 8; ++i) {
            float p = 0.f;
#pragma unroll
            for (int j = 0; j < 4; ++j) p += tanhf(acc[i][j] + tq[j]) * vv[j];
            p += __shfl_down(p, 8, 16);
            p += __shfl_down(p, 4, 16);
            p += __shfl_down(p, 2, 16);
            p += __shfl_down(p, 1, 16);
            if (tx == 0) fscore[ty * 8 + i] += p;
        }
    }
    __syncthreads();
    if (tid < 128) scores[(size_t)b * S_ + s0 + tid] = fscore[tid];
}

// ---------------- K3: softmax over S per batch ------------------------------
__global__ void softmax_kernel(const float* __restrict__ scores, float* __restrict__ wout) {
    int b = blockIdx.x;
    int tid = threadIdx.x;
    __shared__ float red[256];
    float v[8];
    float m = -1e30f;
#pragma unroll
    for (int i = 0; i < 8; ++i) {
        v[i] = scores[(size_t)b * S_ + tid + i * 256];
        m = fmaxf(m, v[i]);
    }
    red[tid] = m; __syncthreads();
    for (int off = 128; off > 0; off >>= 1) {
        if (tid < off) red[tid] = fmaxf(red[tid], red[tid + off]);
        __syncthreads();
    }
    m = red[0];
    __syncthreads();
    float s = 0.f;
#pragma unroll
    for (int i = 0; i < 8; ++i) { v[i] = __expf(v[i] - m); s += v[i]; }
    red[tid] = s; __syncthreads();
    for (int off = 128; off > 0; off >>= 1) {
        if (tid < off) red[tid] += red[tid + off];
        __syncthreads();
    }
    float inv = 1.f / red[0];
#pragma unroll
    for (int i = 0; i < 8; ++i) wout[(size_t)b * S_ + tid + i * 256] = v[i] * inv;
}

// ---------------- K4: context = sum_s w * values — streaming float4 ---------
__global__ void context_kernel(const float* __restrict__ values, const float* __restrict__ w,
                               float* __restrict__ ctx) {
    int b   = blockIdx.x;     // 32
    int sc  = blockIdx.y;     // 16 chunks of 128 s
    int tid = threadIdx.x;    // 256
    __shared__ float ws_[128];
    if (tid < 128) ws_[tid] = w[(size_t)b * S_ + sc * 128 + tid];
    __syncthreads();
    const float4* vp = (const float4*)(values + ((size_t)b * S_ + sc * 128) * DV) + tid;
    float ax = 0.f, ay = 0.f, az = 0.f, aw = 0.f;
#pragma unroll 4
    for (int s = 0; s < 128; ++s) {
        float4 v = vp[(size_t)s * 256];
        float wv = ws_[s];
        ax += wv * v.x; ay += wv * v.y; az += wv * v.z; aw += wv * v.w;
    }
    float* c = ctx + b * DV + tid * 4;
    atomicAdd(c + 0, ax); atomicAdd(c + 1, ay);
    atomicAdd(c + 2, az); atomicAdd(c + 3, aw);
}

// ---------------- launch ----------------------------------------------------
extern "C" void kernel_launch(void* const* d_in, const int* in_sizes, int n_in,
                              void* d_out, int out_size, void* d_ws, size_t ws_size,
                              hipStream_t stream) {
    const float* query  = (const float*)d_in[0];
    const float* values = (const float*)d_in[1];
    const float* W1     = (const float*)d_in[2];
    const float* b1     = (const float*)d_in[3];
    const float* W2     = (const float*)d_in[4];
    const float* b2     = (const float*)d_in[5];
    const float* V      = (const float*)d_in[6];
    // bV (d_in[7]) shifts all scores equally -> softmax-invariant.

    float* out  = (float*)d_out;
    float* ctx  = out;                 // [32, 1024]
    float* wout = out + B_ * DV;       // [32, 2048]

    char* ws = (char*)d_ws;
    const size_t W1T_BYTES = (size_t)U_ * DV * 2;              // 2 MB
    const size_t T_BYTES   = (size_t)B_ * U_ * 4;              // 128 KB
    const size_t SC_BYTES  = (size_t)B_ * S_ * 4;              // 256 KB
    const size_t ABF_BYTES = (size_t)B_ * S_ * DV * 2;         // 128 MB

    if (ws_size >= W1T_BYTES + T_BYTES + SC_BYTES + ABF_BYTES) {
        // fast path: R4 composition with LDS-bounce cvt (both sides coalesced)
        unsigned short* W1T = (unsigned short*)ws;
        float* t      = (float*)(ws + W1T_BYTES);
        float* scores = t + B_ * U_;
        char*  AbfT   = (char*)(scores + B_ * S_);

        init_kernel   <<<dim3(256),      256, 0, stream>>>(b1, b2, t, ctx, scores);
        projq_kernel  <<<dim3(32, 16),   256, 0, stream>>>(query, W2, t);
        cvt_lds       <<<dim3(256, 16),  256, 0, stream>>>(values, AbfT);
        prep_w1t      <<<dim3(16, 16),   256, 0, stream>>>(W1, W1T);
        scores_mfma8  <<<dim3(1024),     512, 0, stream>>>(AbfT, W1T, t, V, scores);
        softmax_kernel<<<dim3(32),       256, 0, stream>>>(scores, wout);
        context_kernel<<<dim3(32, 16),   256, 0, stream>>>(values, wout, ctx);
    } else if (ws_size >= W1T_BYTES + T_BYTES + SC_BYTES) {
        // mid path: fp32 A converted in-kernel, bf16 W1T, MFMA
        unsigned short* W1T = (unsigned short*)ws;
        float* t      = (float*)(ws + W1T_BYTES);
        float* scores = t + B_ * U_;

        init_kernel   <<<dim3(256),      256, 0, stream>>>(b1, b2, t, ctx, scores);
        projq_kernel  <<<dim3(32, 16),   256, 0, stream>>>(query, W2, t);
        prep_w1t      <<<dim3(16, 16),   256, 0, stream>>>(W1, W1T);
        scores_mfma<false><<<dim3(2048), 256, 0, stream>>>(values, W1T, t, V, scores);
        softmax_kernel<<<dim3(32),       256, 0, stream>>>(scores, wout);
        context_kernel<<<dim3(32, 16),   256, 0, stream>>>(values, wout, ctx);
    } else {
        // low path: round-1 fp32 vector kernel (384 KB ws, proven)
        float* t      = (float*)ws;
        float* scores = t + B_ * U_;

        init_kernel   <<<dim3(256),      256, 0, stream>>>(b1, b2, t, ctx, scores);
        projq_kernel  <<<dim3(32, 16),   256, 0, stream>>>(query, W2, t);
        scores_vec    <<<dim3(16, 32),   256, 0, stream>>>(values, W1, t, V, scores);
        softmax_kernel<<<dim3(32),       256, 0, stream>>>(scores, wout);
        context_kernel<<<dim3(32, 16),   256, 0, stream>>>(values, wout, ctx);
    }
}